// Round 27
// baseline (205.200 us; speedup 1.0000x reference)
//
#include <hip/hip_runtime.h>
#include <cstdint>
#include <cstddef>

#define Tt 2048
#define Bb 2
#define Ee 1024
#define Hh 16
#define HD 64
#define BHh (Bb*Hh)
#define Mm (Tt*Bb)

typedef short bf16x8 __attribute__((ext_vector_type(8)));
typedef float f32x4  __attribute__((ext_vector_type(4)));

#define MFMA16(a,b,c) __builtin_amdgcn_mfma_f32_16x16x32_bf16(a, b, c, 0, 0, 0)

// Scalar software RNE f32->bf16 (epilogue scatter paths only).
__device__ __forceinline__ unsigned short f2bf(float f) {
    unsigned int u = __builtin_bit_cast(unsigned int, f);
    u += 0x7FFFu + ((u >> 16) & 1u);        // RNE
    return (unsigned short)(u >> 16);
}
// HW packed f32->bf16 (RNE) — R26-validated bit-identical to software path.
__device__ __forceinline__ unsigned int pack2bf(float lo, float hi) {
    unsigned int r;
    asm("v_cvt_pk_bf16_f32 %0, %1, %2" : "=v"(r) : "v"(lo), "v"(hi));
    return r;
}

// ---- swizzled LDS addressing (dword index) --------------------------------
// attn K/V tiles: 64 rows x 32 dw. XOR (row&7)<<2 -> b128 frag reads and
// staging writes bank-uniform (verified R15: SQ_LDS_BANK_CONFLICT = 0).
__device__ __forceinline__ int swzA(int row, int dwcol) {
    return (row*32 + dwcol) ^ ((row & 7) << 2);
}
// gemm tiles: 128 rows x 16 dw. XOR (row&3)<<2.
__device__ __forceinline__ int swzG(int row, int dwcol) {
    return (row*16 + dwcol) ^ ((row & 3) << 2);
}

// R7-proven split-convention fragment load, pitch 66 ushorts (avg_probs).
__device__ __forceinline__ bf16x8 ldfrag(const unsigned short* base, int row, int col) {
    const unsigned int* p = (const unsigned int*)(base + row*66 + col);
    const unsigned int* q = (const unsigned int*)(base + row*66 + col + 16);
    uint4 u;
    u.x = p[0]; u.y = p[1];
    u.z = q[0]; u.w = q[1];
    return __builtin_bit_cast(bf16x8, u);
}

// ---------------------------------------------------------------------------
// f32 -> bf16 prepack (RNE), vectorized x8. n8 = n/8.
// ---------------------------------------------------------------------------
__global__ __launch_bounds__(256)
void to_bf16(const float* __restrict__ src, unsigned short* __restrict__ dst, int n8)
{
    const int stride = gridDim.x * 256;
    for (int i = blockIdx.x*256 + threadIdx.x; i < n8; i += stride) {
        const float4 a = ((const float4*)src)[2*i];
        const float4 b = ((const float4*)src)[2*i + 1];
        const uint4 u = {pack2bf(a.x,a.y), pack2bf(a.z,a.w),
                         pack2bf(b.x,b.y), pack2bf(b.z,b.w)};
        ((uint4*)dst)[i] = u;
    }
}

// ---------------------------------------------------------------------------
// MFMA GEMM on bf16: C[M,N] = A[M,K]*W[N,K]^T + bias[N].
// 128x128 tile, BK=32, 4 waves (2x2), wave = 64x64 out.
// Double-buffered LDS + register prefetch, 1 barrier/K-step (R21-validated).
// MODE 0 (R27): V stored PERMUTED [bh][tile=s>>6][d][col(s&63)] so attn can
// single-b128-read V fragments (perm formula HW-validated in R15):
// col(sc) = (sc&3) | ((sc>>4&1)<<2) | ((sc>>2&3)<<3) | ((sc>>5)<<5).
// ---------------------------------------------------------------------------
template<int MODE>
__global__ __launch_bounds__(256)
void gemm_mfma(const unsigned short* __restrict__ A, const unsigned short* __restrict__ W,
               const float* __restrict__ bias, float* __restrict__ Cout,
               unsigned short* __restrict__ qbuf, unsigned short* __restrict__ kbuf,
               unsigned short* __restrict__ vbuf, int N, int K)
{
    __shared__ __align__(16) unsigned int AsDW[2][128*16];
    __shared__ __align__(16) unsigned int WsDW[2][128*16];
    const int tid  = threadIdx.x;
    const int bm   = blockIdx.y * 128;
    const int bn   = blockIdx.x * 128;
    const int w    = tid >> 6;
    const int lane = tid & 63;
    const int lr   = lane & 15;
    const int lg   = lane >> 4;
    const int wm   = (w >> 1) * 64;
    const int wn   = (w & 1) * 64;

    f32x4 acc[4][4];
#pragma unroll
    for (int m = 0; m < 4; ++m)
#pragma unroll
        for (int n = 0; n < 4; ++n)
            acc[m][n] = f32x4{0.f, 0.f, 0.f, 0.f};

    const int r1  = tid >> 2;           // staging row 0..63 (+64)
    const int cdw = (tid & 3) * 4;      // dword col 0,4,8,12

    // ---- prologue: stage K-step 0 into buf 0 ----
    {
        const uint4 a0 = *(const uint4*)&A[(size_t)(bm + r1)      * K + cdw*2];
        const uint4 a1 = *(const uint4*)&A[(size_t)(bm + r1 + 64) * K + cdw*2];
        const uint4 w0 = *(const uint4*)&W[(size_t)(bn + r1)      * K + cdw*2];
        const uint4 w1 = *(const uint4*)&W[(size_t)(bn + r1 + 64) * K + cdw*2];
        *(uint4*)(AsDW[0] + swzG(r1,      cdw)) = a0;
        *(uint4*)(AsDW[0] + swzG(r1 + 64, cdw)) = a1;
        *(uint4*)(WsDW[0] + swzG(r1,      cdw)) = w0;
        *(uint4*)(WsDW[0] + swzG(r1 + 64, cdw)) = w1;
        __syncthreads();
    }

    int cur = 0;
    for (int k0 = 0; k0 < K; k0 += 32) {
        const bool has_next = (k0 + 32 < K);
        uint4 an0, an1, wn0, wn1;
        if (has_next) {
            an0 = *(const uint4*)&A[(size_t)(bm + r1)      * K + k0 + 32 + cdw*2];
            an1 = *(const uint4*)&A[(size_t)(bm + r1 + 64) * K + k0 + 32 + cdw*2];
            wn0 = *(const uint4*)&W[(size_t)(bn + r1)      * K + k0 + 32 + cdw*2];
            wn1 = *(const uint4*)&W[(size_t)(bn + r1 + 64) * K + k0 + 32 + cdw*2];
        }

        const unsigned int* Ac = AsDW[cur];
        const unsigned int* Wc = WsDW[cur];
        bf16x8 af[4], wf[4];
#pragma unroll
        for (int i = 0; i < 4; ++i) {
            af[i] = __builtin_bit_cast(bf16x8, *(const uint4*)(Ac + swzG(wm + 16*i + lr, 4*lg)));
            wf[i] = __builtin_bit_cast(bf16x8, *(const uint4*)(Wc + swzG(wn + 16*i + lr, 4*lg)));
        }
#pragma unroll
        for (int m = 0; m < 4; ++m)
#pragma unroll
            for (int n = 0; n < 4; ++n)
                acc[m][n] = MFMA16(af[m], wf[n], acc[m][n]);

        if (has_next) {
            *(uint4*)(AsDW[cur ^ 1] + swzG(r1,      cdw)) = an0;
            *(uint4*)(AsDW[cur ^ 1] + swzG(r1 + 64, cdw)) = an1;
            *(uint4*)(WsDW[cur ^ 1] + swzG(r1,      cdw)) = wn0;
            *(uint4*)(WsDW[cur ^ 1] + swzG(r1 + 64, cdw)) = wn1;
        }
        __syncthreads();
        cur ^= 1;
    }

    // D-layout: value(lane,reg) of subtile (msub,nsub) ->
    // C[bm+wm+16*msub+4*lg+reg][bn+wn+16*nsub+lr]
#pragma unroll
    for (int nsub = 0; nsub < 4; ++nsub) {
        const int n0 = bn + wn + 16*nsub + lr;
        const float bv = bias[n0];
#pragma unroll
        for (int msub = 0; msub < 4; ++msub) {
#pragma unroll
            for (int reg = 0; reg < 4; ++reg) {
                const int m = bm + wm + 16*msub + 4*lg + reg;
                float v = acc[msub][nsub][reg] + bv;
                if (MODE == 0) {
                    const int which = n0 >> 10;
                    const int e0 = n0 & 1023;
                    const int h = e0 >> 6, d0 = e0 & 63;
                    const int t = m >> 1, bb = m & 1;
                    if (which == 0) v *= 0.125f;
                    if (which == 2) {
                        // V: permuted layout [bh][tile][d0][col(sc)]
                        const int tile = t >> 6, sc = t & 63;
                        const int col = (sc & 3) | (((sc >> 4) & 1) << 2) |
                                        (((sc >> 2) & 3) << 3) | ((sc >> 5) << 5);
                        vbuf[(((size_t)(bb*Hh + h) * 32 + tile) * 64 + d0) * 64 + col] = f2bf(v);
                    } else {
                        unsigned short* dst = (which == 0) ? qbuf : kbuf;
                        dst[((size_t)(bb*Hh + h) * Tt + t) * HD + d0] = f2bf(v);
                    }
                } else {
                    Cout[(size_t)m * N + n0] = v;
                }
            }
        }
    }
}

// ---------------------------------------------------------------------------
// MFMA fused attention (R23 config: 128-row Q-tile, 8 waves, dbuf+prefetch,
// 1 barrier/tile). R27: V is pre-permuted in global (gemm0 epilogue), so
// V staging = straight coalesced uint4 copy (same map as K) and PV V
// fragments are SINGLE ds_read_b128 on the zero-conflict swzA layout.
// ---------------------------------------------------------------------------
__global__ __launch_bounds__(512)
void attn_mfma(const unsigned short* __restrict__ qb, const unsigned short* __restrict__ kb,
               const unsigned short* __restrict__ vb, const float* __restrict__ mask,
               unsigned short* __restrict__ attnb, float* __restrict__ lbuf)
{
    __shared__ __align__(16) unsigned int KsDW[2][64*32];   // K tiles (buf0 also Q staging)
    __shared__ __align__(16) unsigned int VtDW[2][64*32];   // V tiles (pre-permuted)
    __shared__ float l_sh[128];

    const int tid  = threadIdx.x;
    const int bid  = blockIdx.x;
    const int wid  = (bid & 7) * 64 + (bid >> 3);   // XCD-aware remap (512=8*64)
    const int bh   = wid & 31;             // b*16+h
    const int t0   = (wid >> 5) * 128;
    const int w    = tid >> 6;             // wave 0..7
    const int lane = tid & 63;
    const int lr   = lane & 15;
    const int lg   = lane >> 4;            // k-group 0..3
    const int b = bh >> 4, h = bh & 15;

    const unsigned short* __restrict__ Qg = qb + (size_t)bh * Tt * HD;
    const unsigned short* __restrict__ Kg = kb + (size_t)bh * Tt * HD;
    const unsigned short* __restrict__ Vg = vb + (size_t)bh * Tt * HD;  // [32][64][64] permuted

    const int str = tid >> 3;              // staging row 0..63
    const int sdw = (tid & 7) * 4;         // staging dword col

    // ---- Q fragments to registers (B-operand of swapped QK^T) ----
    bf16x8 qf[2];   // [d-half]
    for (int half = 0; half < 2; ++half) {
        __syncthreads();
        *(uint4*)(KsDW[0] + swzA(str, sdw)) =
            *(const uint4*)&Qg[(size_t)(t0 + half*64 + str) * HD + sdw*2];
        __syncthreads();
        if ((w >> 2) == half) {
            const int r = 16*(w & 3) + lr;
            qf[0] = __builtin_bit_cast(bf16x8, *(const uint4*)(KsDW[0] + swzA(r, 4*lg)));
            qf[1] = __builtin_bit_cast(bf16x8, *(const uint4*)(KsDW[0] + swzA(r, 16 + 4*lg)));
        }
    }

    f32x4 oacc[4];
#pragma unroll
    for (int d = 0; d < 4; ++d)
        oacc[d] = f32x4{0.f, 0.f, 0.f, 0.f};
    float lacc = 0.f;

    // ---- prologue: stage tile 0 into buf 0 ----
    {
        const uint4 k0r = *(const uint4*)&Kg[(size_t)str * HD + sdw*2];
        const uint4 v0r = *(const uint4*)&Vg[(size_t)str * 64 + sdw*2];   // tile 0
        __syncthreads();   // Q fragment reads of KsDW[0] complete
        *(uint4*)(KsDW[0] + swzA(str, sdw)) = k0r;
        *(uint4*)(VtDW[0] + swzA(str, sdw)) = v0r;
        __syncthreads();
    }

    int cur = 0;
    for (int s0 = 0; s0 < Tt; s0 += 64) {
        const bool has_next = (s0 + 64 < Tt);
        // ---- issue prefetch for tile i+1 (latency hides under compute) ----
        uint4 kn, vn;
        if (has_next) {
            kn = *(const uint4*)&Kg[(size_t)(s0 + 64 + str) * HD + sdw*2];
            vn = *(const uint4*)&Vg[((size_t)((s0 >> 6) + 1) * 64 + str) * 64 + sdw*2];
        }

        const unsigned int* Kc = KsDW[cur];
        const unsigned int* VcDW = VtDW[cur];

        // QK^T (swapped): sacc[ssub] = S^T 16x16 tile (row=s, col=t)
        f32x4 sacc[4];
#pragma unroll
        for (int ssub = 0; ssub < 4; ++ssub) {
            const bf16x8 a0 = __builtin_bit_cast(bf16x8,
                *(const uint4*)(Kc + swzA(16*ssub + lr, 4*lg)));
            const bf16x8 a1 = __builtin_bit_cast(bf16x8,
                *(const uint4*)(Kc + swzA(16*ssub + lr, 16 + 4*lg)));
            f32x4 z = {0.f, 0.f, 0.f, 0.f};
            z = MFMA16(a0, qf[0], z);
            z = MFMA16(a1, qf[1], z);
            sacc[ssub] = z;
        }

        // exp(score + mask): P packed into PV A-fragments; l partial
        unsigned int pw[8];
        {
            float lt = 0.f;
            const float* __restrict__ mrow =
                &mask[(size_t)(t0 + 16*w + lr) * Tt + s0];
#pragma unroll
            for (int ssub = 0; ssub < 4; ++ssub) {
                const float4 mv = *(const float4*)&mrow[16*ssub + 4*lg];
                const float e0 = __expf(sacc[ssub][0] + mv.x);
                const float e1 = __expf(sacc[ssub][1] + mv.y);
                const float e2 = __expf(sacc[ssub][2] + mv.z);
                const float e3 = __expf(sacc[ssub][3] + mv.w);
                lt += (e0 + e1) + (e2 + e3);
                pw[ssub*2]     = pack2bf(e0, e1);
                pw[ssub*2 + 1] = pack2bf(e2, e3);
            }
            lt += __shfl_xor(lt, 16);
            lt += __shfl_xor(lt, 32);
            lacc += lt;
        }

        // PV: O[t][d] += P * V — V pre-permuted, single b128 per fragment
        const uint4 ua = {pw[0], pw[1], pw[2], pw[3]};
        const uint4 ub = {pw[4], pw[5], pw[6], pw[7]};
#pragma unroll
        for (int dsub = 0; dsub < 4; ++dsub) {
            const bf16x8 b0 = __builtin_bit_cast(bf16x8,
                *(const uint4*)(VcDW + swzA(16*dsub + lr, 4*lg)));
            const bf16x8 b1 = __builtin_bit_cast(bf16x8,
                *(const uint4*)(VcDW + swzA(16*dsub + lr, 16 + 4*lg)));
            oacc[dsub] = MFMA16(__builtin_bit_cast(bf16x8, ua), b0, oacc[dsub]);
            oacc[dsub] = MFMA16(__builtin_bit_cast(bf16x8, ub), b1, oacc[dsub]);
        }

        // ---- write prefetched tile i+1 into the alternate buffer ----
        if (has_next) {
            *(uint4*)(KsDW[cur ^ 1] + swzA(str, sdw)) = kn;
            *(uint4*)(VtDW[cur ^ 1] + swzA(str, sdw)) = vn;
        }
        __syncthreads();
        cur ^= 1;
    }

    if (lg == 0) l_sh[16*w + lr] = lacc;
    __syncthreads();
#pragma unroll
    for (int reg = 0; reg < 4; ++reg) {
        const int tl = 16*w + 4*lg + reg;
        const float inv = 1.f / l_sh[tl];
        const int t = t0 + tl;
#pragma unroll
        for (int dsub = 0; dsub < 4; ++dsub)
            attnb[((size_t)t * Bb + b) * Ee + h*HD + dsub*16 + lr] =
                f2bf(oacc[dsub][reg] * inv);
    }
    if (lg == 0)
        lbuf[(size_t)bh * Tt + t0 + 16*w + lr] = lacc;
}

// ---------------------------------------------------------------------------
// MFMA avg_w pass (bf16 Q/K in): block = (b, 64 t, 64 s); loops 16 heads.
// Double-buffered h-loop (R23-validated).
// ---------------------------------------------------------------------------
__global__ __launch_bounds__(256)
void avg_probs_mfma(const unsigned short* __restrict__ qb, const unsigned short* __restrict__ kb,
                    const float* __restrict__ mask, const float* __restrict__ lbuf,
                    float* __restrict__ avg)
{
    __shared__ __align__(16) unsigned short Qs[2][64*66];
    __shared__ __align__(16) unsigned short Ksh[2][64*66];
    __shared__ float linv[16][64];

    const int tid  = threadIdx.x;
    const int b    = blockIdx.z;
    const int t0   = blockIdx.y * 64;
    const int s0   = blockIdx.x * 64;
    const int w    = tid >> 6;
    const int lane = tid & 63;
    const int lr   = lane & 15;
    const int lg   = lane >> 4;

    const int str = tid >> 2;              // staging row 0..63
    const int stc = (tid & 3) * 16;        // staging col (ushorts)

    {   // stage 1/(16*l) for all 16 heads + head 0's Q/K tiles
        const int hh = tid >> 4, tl = (tid & 15) * 4;
        const float4 lv = *(const float4*)&lbuf[(size_t)(b*Hh + hh) * Tt + t0 + tl];
        linv[hh][tl+0] = 1.f / (16.f * lv.x);
        linv[hh][tl+1] = 1.f / (16.f * lv.y);
        linv[hh][tl+2] = 1.f / (16.f * lv.z);
        linv[hh][tl+3] = 1.f / (16.f * lv.w);

        const unsigned short* Qp = &qb[((size_t)(b*Hh) * Tt + t0 + str) * HD + stc];
        const unsigned short* Kp = &kb[((size_t)(b*Hh) * Tt + s0 + str) * HD + stc];
        const uint4 q0 = *(const uint4*)Qp;
        const uint4 q1 = *(const uint4*)(Qp + 8);
        const uint4 k0 = *(const uint4*)Kp;
        const uint4 k1 = *(const uint4*)(Kp + 8);
        *(uint4*)&Qs[0][str*66 + stc]      = q0;
        *(uint4*)&Qs[0][str*66 + stc + 8]  = q1;
        *(uint4*)&Ksh[0][str*66 + stc]     = k0;
        *(uint4*)&Ksh[0][str*66 + stc + 8] = k1;
        __syncthreads();
    }

    // mask fragments (value(lane,reg) at t=t0+16w+4lg+reg, s=s0+16ssub+lr)
    f32x4 mf[4];
#pragma unroll
    for (int ssub = 0; ssub < 4; ++ssub)
#pragma unroll
        for (int reg = 0; reg < 4; ++reg)
            mf[ssub][reg] = mask[(size_t)(t0 + 16*w + 4*lg + reg) * Tt + s0 + 16*ssub + lr];

    f32x4 av[4];
#pragma unroll
    for (int ssub = 0; ssub < 4; ++ssub) av[ssub] = f32x4{0.f, 0.f, 0.f, 0.f};

    int cur = 0;
    for (int h = 0; h < Hh; ++h) {
        const bool has_next = (h + 1 < Hh);
        uint4 qn0, qn1, kn0, kn1;
        if (has_next) {
            const unsigned short* Qp = &qb[((size_t)(b*Hh + h + 1) * Tt + t0 + str) * HD + stc];
            const unsigned short* Kp = &kb[((size_t)(b*Hh + h + 1) * Tt + s0 + str) * HD + stc];
            qn0 = *(const uint4*)Qp;
            qn1 = *(const uint4*)(Qp + 8);
            kn0 = *(const uint4*)Kp;
            kn1 = *(const uint4*)(Kp + 8);
        }

        const unsigned short* Qc = &Qs[cur][0];
        const unsigned short* Kc = &Ksh[cur][0];

        const float lv0 = linv[h][16*w + 4*lg + 0];
        const float lv1 = linv[h][16*w + 4*lg + 1];
        const float lv2 = linv[h][16*w + 4*lg + 2];
        const float lv3 = linv[h][16*w + 4*lg + 3];

        const bf16x8 af0 = ldfrag(Qc, 16*w + lr, 4*lg);
        const bf16x8 af1 = ldfrag(Qc, 16*w + lr, 32 + 4*lg);
#pragma unroll
        for (int ssub = 0; ssub < 4; ++ssub) {
            const bf16x8 bf0 = ldfrag(Kc, 16*ssub + lr, 4*lg);
            const bf16x8 bf1 = ldfrag(Kc, 16*ssub + lr, 32 + 4*lg);
            f32x4 z = {0.f, 0.f, 0.f, 0.f};
            z = MFMA16(af0, bf0, z);
            z = MFMA16(af1, bf1, z);
            av[ssub][0] += __expf(z[0] + mf[ssub][0]) * lv0;
            av[ssub][1] += __expf(z[1] + mf[ssub][1]) * lv1;
            av[ssub][2] += __expf(z[2] + mf[ssub][2]) * lv2;
            av[ssub][3] += __expf(z[3] + mf[ssub][3]) * lv3;
        }

        if (has_next) {
            *(uint4*)&Qs[cur ^ 1][str*66 + stc]      = qn0;
            *(uint4*)&Qs[cur ^ 1][str*66 + stc + 8]  = qn1;
            *(uint4*)&Ksh[cur ^ 1][str*66 + stc]     = kn0;
            *(uint4*)&Ksh[cur ^ 1][str*66 + stc + 8] = kn1;
        }
        __syncthreads();
        cur ^= 1;
    }

#pragma unroll
    for (int ssub = 0; ssub < 4; ++ssub)
#pragma unroll
        for (int reg = 0; reg < 4; ++reg)
            avg[((size_t)b * Tt + t0 + 16*w + 4*lg + reg) * Tt + s0 + 16*ssub + lr] =
                av[ssub][reg];
}

// ---------------------------------------------------------------------------
extern "C" void kernel_launch(void* const* d_in, const int* in_sizes, int n_in,
                              void* d_out, int out_size, void* d_ws, size_t ws_size,
                              hipStream_t stream)
{
    (void)in_sizes; (void)n_in; (void)out_size; (void)ws_size;
    const float* query = (const float*)d_in[0];   // [T,B,E]
    const float* mask  = (const float*)d_in[1];   // [T,T]
    const float* Wqkv  = (const float*)d_in[2];   // [3E,E]
    const float* bqkv  = (const float*)d_in[3];   // [3E]
    const float* Wout  = (const float*)d_in[4];   // [E,E]
    const float* bout  = (const float*)d_in[5];   // [E]

    float* out = (float*)d_out;                   // [T,B,E]
    float* avg = out + (size_t)Tt * Bb * Ee;      // [B,T,T]

    const size_t S1 = (size_t)BHh * Tt * HD;      // 4,194,304
    unsigned short* wsu     = (unsigned short*)d_ws;
    unsigned short* qbuf    = wsu;                 // bf16, Q pre-scaled
    unsigned short* kbuf    = qbuf + S1;
    unsigned short* vbuf    = kbuf + S1;           // bf16, PERMUTED [bh][32][64][64]
    unsigned short* attnb   = vbuf + S1;           // bf16 [T*B][E]
    unsigned short* querybf = attnb + (size_t)Mm * Ee;
    unsigned short* wqkvbf  = querybf + (size_t)Mm * Ee;
    unsigned short* woutbf  = wqkvbf + (size_t)3 * Ee * Ee;
    float*          lbuf    = (float*)(woutbf + (size_t)Ee * Ee);

    // 0) prepack f32 weights/activations to bf16 (RNE)
    to_bf16<<<1024, 256, 0, stream>>>(query, querybf, (Mm*Ee)/8);
    to_bf16<<<1024, 256, 0, stream>>>(Wqkv, wqkvbf, (3*Ee*Ee)/8);
    to_bf16<<<512,  256, 0, stream>>>(Wout, woutbf, (Ee*Ee)/8);

    // 1) fused QKV projection (MFMA, dbuf; V stored permuted, Q pre-scaled)
    gemm_mfma<0><<<dim3(3072/128, Mm/128), 256, 0, stream>>>(
        querybf, wqkvbf, bqkv, nullptr, qbuf, kbuf, vbuf, 3072, Ee);
    // 2) MFMA fused attention — 128-row Q-tiles, dbuf, b128 V reads
    attn_mfma<<<dim3(BHh * (Tt/128)), 512, 0, stream>>>(
        qbuf, kbuf, vbuf, mask, attnb, lbuf);
    // 3) head-averaged probs (MFMA, dbuf h-loop)
    avg_probs_mfma<<<dim3(Tt/64, Tt/64, Bb), 256, 0, stream>>>(
        qbuf, kbuf, mask, lbuf, avg);
    // 4) output projection (MFMA, dbuf)
    gemm_mfma<1><<<dim3(Ee/128, Mm/128), 256, 0, stream>>>(
        attnb, woutbf, bout, out, nullptr, nullptr, nullptr, Ee, Ee);
}

// Round 28
// 198.087 us; speedup vs baseline: 1.0359x; 1.0359x over previous
//
#include <hip/hip_runtime.h>
#include <cstdint>
#include <cstddef>

#define Tt 2048
#define Bb 2
#define Ee 1024
#define Hh 16
#define HD 64
#define BHh (Bb*Hh)
#define Mm (Tt*Bb)

typedef short bf16x8 __attribute__((ext_vector_type(8)));
typedef float f32x4  __attribute__((ext_vector_type(4)));

#define MFMA16(a,b,c) __builtin_amdgcn_mfma_f32_16x16x32_bf16(a, b, c, 0, 0, 0)

// Scalar software RNE f32->bf16 (epilogue scatter paths only).
__device__ __forceinline__ unsigned short f2bf(float f) {
    unsigned int u = __builtin_bit_cast(unsigned int, f);
    u += 0x7FFFu + ((u >> 16) & 1u);        // RNE
    return (unsigned short)(u >> 16);
}
// HW packed f32->bf16 (RNE) — R26-validated bit-identical to software path.
__device__ __forceinline__ unsigned int pack2bf(float lo, float hi) {
    unsigned int r;
    asm("v_cvt_pk_bf16_f32 %0, %1, %2" : "=v"(r) : "v"(lo), "v"(hi));
    return r;
}

// ---- swizzled LDS addressing (dword index) --------------------------------
// attn K tile: 64 rows x 32 dw. XOR (row&7)<<2 -> b128 frag reads and
// staging writes bank-uniform (verified R15: SQ_LDS_BANK_CONFLICT = 0).
__device__ __forceinline__ int swzA(int row, int dwcol) {
    return (row*32 + dwcol) ^ ((row & 7) << 2);
}
// gemm tiles: 128 rows x 16 dw. XOR (row&3)<<2.
__device__ __forceinline__ int swzG(int row, int dwcol) {
    return (row*16 + dwcol) ^ ((row & 3) << 2);
}

// R7-proven split-convention fragment load, pitch 66 ushorts.
// slot j<4 -> col+j, j>=4 -> col+16+(j-4). Used for PV's V operand (forced
// by P's register k-slot layout) and by avg_probs.
__device__ __forceinline__ bf16x8 ldfrag(const unsigned short* base, int row, int col) {
    const unsigned int* p = (const unsigned int*)(base + row*66 + col);
    const unsigned int* q = (const unsigned int*)(base + row*66 + col + 16);
    uint4 u;
    u.x = p[0]; u.y = p[1];
    u.z = q[0]; u.w = q[1];
    return __builtin_bit_cast(bf16x8, u);
}

// ---------------------------------------------------------------------------
// f32 -> bf16 prepack (RNE), vectorized x8. n8 = n/8.
// ---------------------------------------------------------------------------
__global__ __launch_bounds__(256)
void to_bf16(const float* __restrict__ src, unsigned short* __restrict__ dst, int n8)
{
    const int stride = gridDim.x * 256;
    for (int i = blockIdx.x*256 + threadIdx.x; i < n8; i += stride) {
        const float4 a = ((const float4*)src)[2*i];
        const float4 b = ((const float4*)src)[2*i + 1];
        const uint4 u = {pack2bf(a.x,a.y), pack2bf(a.z,a.w),
                         pack2bf(b.x,b.y), pack2bf(b.z,b.w)};
        ((uint4*)dst)[i] = u;
    }
}

// ---------------------------------------------------------------------------
// MFMA GEMM on bf16: C[M,N] = A[M,K]*W[N,K]^T + bias[N].
// 128x128 tile, BK=32, 4 waves (2x2), wave = 64x64 out.
// Double-buffered LDS + register prefetch, 1 barrier/K-step (R21-validated).
// ---------------------------------------------------------------------------
template<int MODE>
__global__ __launch_bounds__(256)
void gemm_mfma(const unsigned short* __restrict__ A, const unsigned short* __restrict__ W,
               const float* __restrict__ bias, float* __restrict__ Cout,
               unsigned short* __restrict__ qbuf, unsigned short* __restrict__ kbuf,
               unsigned short* __restrict__ vbuf, int N, int K)
{
    __shared__ __align__(16) unsigned int AsDW[2][128*16];
    __shared__ __align__(16) unsigned int WsDW[2][128*16];
    const int tid  = threadIdx.x;
    const int bm   = blockIdx.y * 128;
    const int bn   = blockIdx.x * 128;
    const int w    = tid >> 6;
    const int lane = tid & 63;
    const int lr   = lane & 15;
    const int lg   = lane >> 4;
    const int wm   = (w >> 1) * 64;
    const int wn   = (w & 1) * 64;

    f32x4 acc[4][4];
#pragma unroll
    for (int m = 0; m < 4; ++m)
#pragma unroll
        for (int n = 0; n < 4; ++n)
            acc[m][n] = f32x4{0.f, 0.f, 0.f, 0.f};

    const int r1  = tid >> 2;           // staging row 0..63 (+64)
    const int cdw = (tid & 3) * 4;      // dword col 0,4,8,12

    // ---- prologue: stage K-step 0 into buf 0 ----
    {
        const uint4 a0 = *(const uint4*)&A[(size_t)(bm + r1)      * K + cdw*2];
        const uint4 a1 = *(const uint4*)&A[(size_t)(bm + r1 + 64) * K + cdw*2];
        const uint4 w0 = *(const uint4*)&W[(size_t)(bn + r1)      * K + cdw*2];
        const uint4 w1 = *(const uint4*)&W[(size_t)(bn + r1 + 64) * K + cdw*2];
        *(uint4*)(AsDW[0] + swzG(r1,      cdw)) = a0;
        *(uint4*)(AsDW[0] + swzG(r1 + 64, cdw)) = a1;
        *(uint4*)(WsDW[0] + swzG(r1,      cdw)) = w0;
        *(uint4*)(WsDW[0] + swzG(r1 + 64, cdw)) = w1;
        __syncthreads();
    }

    int cur = 0;
    for (int k0 = 0; k0 < K; k0 += 32) {
        const bool has_next = (k0 + 32 < K);
        uint4 an0, an1, wn0, wn1;
        if (has_next) {
            an0 = *(const uint4*)&A[(size_t)(bm + r1)      * K + k0 + 32 + cdw*2];
            an1 = *(const uint4*)&A[(size_t)(bm + r1 + 64) * K + k0 + 32 + cdw*2];
            wn0 = *(const uint4*)&W[(size_t)(bn + r1)      * K + k0 + 32 + cdw*2];
            wn1 = *(const uint4*)&W[(size_t)(bn + r1 + 64) * K + k0 + 32 + cdw*2];
        }

        const unsigned int* Ac = AsDW[cur];
        const unsigned int* Wc = WsDW[cur];
        bf16x8 af[4], wf[4];
#pragma unroll
        for (int i = 0; i < 4; ++i) {
            af[i] = __builtin_bit_cast(bf16x8, *(const uint4*)(Ac + swzG(wm + 16*i + lr, 4*lg)));
            wf[i] = __builtin_bit_cast(bf16x8, *(const uint4*)(Wc + swzG(wn + 16*i + lr, 4*lg)));
        }
#pragma unroll
        for (int m = 0; m < 4; ++m)
#pragma unroll
            for (int n = 0; n < 4; ++n)
                acc[m][n] = MFMA16(af[m], wf[n], acc[m][n]);

        if (has_next) {
            *(uint4*)(AsDW[cur ^ 1] + swzG(r1,      cdw)) = an0;
            *(uint4*)(AsDW[cur ^ 1] + swzG(r1 + 64, cdw)) = an1;
            *(uint4*)(WsDW[cur ^ 1] + swzG(r1,      cdw)) = wn0;
            *(uint4*)(WsDW[cur ^ 1] + swzG(r1 + 64, cdw)) = wn1;
        }
        __syncthreads();
        cur ^= 1;
    }

    // D-layout: value(lane,reg) of subtile (msub,nsub) ->
    // C[bm+wm+16*msub+4*lg+reg][bn+wn+16*nsub+lr]
#pragma unroll
    for (int nsub = 0; nsub < 4; ++nsub) {
        const int n0 = bn + wn + 16*nsub + lr;
        const float bv = bias[n0];
#pragma unroll
        for (int msub = 0; msub < 4; ++msub) {
#pragma unroll
            for (int reg = 0; reg < 4; ++reg) {
                const int m = bm + wm + 16*msub + 4*lg + reg;
                float v = acc[msub][nsub][reg] + bv;
                if (MODE == 0) {
                    const int which = n0 >> 10;
                    const int e0 = n0 & 1023;
                    const int h = e0 >> 6, d0 = e0 & 63;
                    if (which == 0) v *= 0.125f;
                    unsigned short* dst = (which == 0) ? qbuf : (which == 1) ? kbuf : vbuf;
                    dst[((size_t)((m & 1)*Hh + h) * Tt + (m >> 1)) * HD + d0] = f2bf(v);
                } else {
                    Cout[(size_t)m * N + n0] = v;
                }
            }
        }
    }
}

// ---------------------------------------------------------------------------
// MFMA fused attention (R23/R26-measured best config: 128-row Q-tile, 8
// waves, dbuf+prefetch, 1 barrier/tile). Probed alternatives all regressed:
// R22 256-row tile (occupancy collapse), R24 split-s (HBM round-trip),
// R27 pre-permuted V (producer scatter cost > consumer gain). Latency-bound
// plateau; further gains need an inline-asm pipelined K-loop.
// ---------------------------------------------------------------------------
__global__ __launch_bounds__(512)
void attn_mfma(const unsigned short* __restrict__ qb, const unsigned short* __restrict__ kb,
               const unsigned short* __restrict__ vb, const float* __restrict__ mask,
               unsigned short* __restrict__ attnb, float* __restrict__ lbuf)
{
    __shared__ __align__(16) unsigned int KsDW[2][64*32];   // K tiles (buf0 also Q staging)
    __shared__ __align__(16) unsigned short Vt[2][64*66];   // V tiles transposed [d][s]
    __shared__ float l_sh[128];

    const int tid  = threadIdx.x;
    const int bid  = blockIdx.x;
    const int wid  = (bid & 7) * 64 + (bid >> 3);   // XCD-aware remap (512=8*64)
    const int bh   = wid & 31;             // b*16+h
    const int t0   = (wid >> 5) * 128;
    const int w    = tid >> 6;             // wave 0..7
    const int lane = tid & 63;
    const int lr   = lane & 15;
    const int lg   = lane >> 4;            // k-group 0..3
    const int b = bh >> 4, h = bh & 15;

    const unsigned short* __restrict__ Qg = qb + (size_t)bh * Tt * HD;
    const unsigned short* __restrict__ Kg = kb + (size_t)bh * Tt * HD;
    const unsigned short* __restrict__ Vg = vb + (size_t)bh * Tt * HD;

    const int str = tid >> 3;              // K staging row 0..63
    const int sdw = (tid & 7) * 4;         // K staging dword col

    // V staging (R10 map): dg fast -> 16-lane groups read 128B contiguous
    const int vdg = tid & 15;              // d-group 0..15
    const int vs2 = tid >> 4;              // s-pair 0..31

    // ---- Q fragments to registers (B-operand of swapped QK^T) ----
    bf16x8 qf[2];   // [d-half]
    for (int half = 0; half < 2; ++half) {
        __syncthreads();
        *(uint4*)(KsDW[0] + swzA(str, sdw)) =
            *(const uint4*)&Qg[(size_t)(t0 + half*64 + str) * HD + sdw*2];
        __syncthreads();
        if ((w >> 2) == half) {
            const int r = 16*(w & 3) + lr;
            qf[0] = __builtin_bit_cast(bf16x8, *(const uint4*)(KsDW[0] + swzA(r, 4*lg)));
            qf[1] = __builtin_bit_cast(bf16x8, *(const uint4*)(KsDW[0] + swzA(r, 16 + 4*lg)));
        }
    }

    f32x4 oacc[4];
#pragma unroll
    for (int d = 0; d < 4; ++d)
        oacc[d] = f32x4{0.f, 0.f, 0.f, 0.f};
    float lacc = 0.f;

    // ---- prologue: stage tile 0 into buf 0 ----
    {
        const uint4 k0r = *(const uint4*)&Kg[(size_t)str * HD + sdw*2];
        const uint2 a0  = *(const uint2*)&Vg[(size_t)(2*vs2)     * HD + vdg*4];
        const uint2 c0  = *(const uint2*)&Vg[(size_t)(2*vs2 + 1) * HD + vdg*4];
        __syncthreads();   // Q fragment reads of KsDW[0] complete
        *(uint4*)(KsDW[0] + swzA(str, sdw)) = k0r;
        unsigned short* vt0 = &Vt[0][0];
        *(unsigned int*)&vt0[(vdg*4+0)*66 + 2*vs2] = (a0.x & 0xFFFFu) | (c0.x << 16);
        *(unsigned int*)&vt0[(vdg*4+1)*66 + 2*vs2] = (a0.x >> 16)     | (c0.x & 0xFFFF0000u);
        *(unsigned int*)&vt0[(vdg*4+2)*66 + 2*vs2] = (a0.y & 0xFFFFu) | (c0.y << 16);
        *(unsigned int*)&vt0[(vdg*4+3)*66 + 2*vs2] = (a0.y >> 16)     | (c0.y & 0xFFFF0000u);
        __syncthreads();
    }

    int cur = 0;
    for (int s0 = 0; s0 < Tt; s0 += 64) {
        const bool has_next = (s0 + 64 < Tt);
        // ---- issue prefetch for tile i+1 (latency hides under compute) ----
        uint4 kn; uint2 van, vcn;
        if (has_next) {
            kn  = *(const uint4*)&Kg[(size_t)(s0 + 64 + str) * HD + sdw*2];
            van = *(const uint2*)&Vg[(size_t)(s0 + 64 + 2*vs2)     * HD + vdg*4];
            vcn = *(const uint2*)&Vg[(size_t)(s0 + 64 + 2*vs2 + 1) * HD + vdg*4];
        }

        const unsigned int* Kc = KsDW[cur];
        const unsigned short* Vc = &Vt[cur][0];

        // QK^T (swapped): sacc[ssub] = S^T 16x16 tile (row=s, col=t)
        f32x4 sacc[4];
#pragma unroll
        for (int ssub = 0; ssub < 4; ++ssub) {
            const bf16x8 a0 = __builtin_bit_cast(bf16x8,
                *(const uint4*)(Kc + swzA(16*ssub + lr, 4*lg)));
            const bf16x8 a1 = __builtin_bit_cast(bf16x8,
                *(const uint4*)(Kc + swzA(16*ssub + lr, 16 + 4*lg)));
            f32x4 z = {0.f, 0.f, 0.f, 0.f};
            z = MFMA16(a0, qf[0], z);
            z = MFMA16(a1, qf[1], z);
            sacc[ssub] = z;
        }

        // exp(score + mask): P packed into PV A-fragments; l partial
        unsigned int pw[8];
        {
            float lt = 0.f;
            const float* __restrict__ mrow =
                &mask[(size_t)(t0 + 16*w + lr) * Tt + s0];
#pragma unroll
            for (int ssub = 0; ssub < 4; ++ssub) {
                const float4 mv = *(const float4*)&mrow[16*ssub + 4*lg];
                const float e0 = __expf(sacc[ssub][0] + mv.x);
                const float e1 = __expf(sacc[ssub][1] + mv.y);
                const float e2 = __expf(sacc[ssub][2] + mv.z);
                const float e3 = __expf(sacc[ssub][3] + mv.w);
                lt += (e0 + e1) + (e2 + e3);
                pw[ssub*2]     = pack2bf(e0, e1);
                pw[ssub*2 + 1] = pack2bf(e2, e3);
            }
            lt += __shfl_xor(lt, 16);
            lt += __shfl_xor(lt, 32);
            lacc += lt;
        }

        // PV: O[t][d] += P * V (split-convention ldfrag on pitch-66 Vt)
        const uint4 ua = {pw[0], pw[1], pw[2], pw[3]};
        const uint4 ub = {pw[4], pw[5], pw[6], pw[7]};
#pragma unroll
        for (int dsub = 0; dsub < 4; ++dsub) {
            const bf16x8 b0 = ldfrag(Vc, 16*dsub + lr, 4*lg);
            const bf16x8 b1 = ldfrag(Vc, 16*dsub + lr, 32 + 4*lg);
            oacc[dsub] = MFMA16(__builtin_bit_cast(bf16x8, ua), b0, oacc[dsub]);
            oacc[dsub] = MFMA16(__builtin_bit_cast(bf16x8, ub), b1, oacc[dsub]);
        }

        // ---- write prefetched tile i+1 into the alternate buffer ----
        if (has_next) {
            *(uint4*)(KsDW[cur ^ 1] + swzA(str, sdw)) = kn;
            unsigned short* vt1 = &Vt[cur ^ 1][0];
            *(unsigned int*)&vt1[(vdg*4+0)*66 + 2*vs2] = (van.x & 0xFFFFu) | (vcn.x << 16);
            *(unsigned int*)&vt1[(vdg*4+1)*66 + 2*vs2] = (van.x >> 16)     | (vcn.x & 0xFFFF0000u);
            *(unsigned int*)&vt1[(vdg*4+2)*66 + 2*vs2] = (van.y & 0xFFFFu) | (vcn.y << 16);
            *(unsigned int*)&vt1[(vdg*4+3)*66 + 2*vs2] = (van.y >> 16)     | (vcn.y & 0xFFFF0000u);
        }
        __syncthreads();
        cur ^= 1;
    }

    if (lg == 0) l_sh[16*w + lr] = lacc;
    __syncthreads();
#pragma unroll
    for (int reg = 0; reg < 4; ++reg) {
        const int tl = 16*w + 4*lg + reg;
        const float inv = 1.f / l_sh[tl];
        const int t = t0 + tl;
#pragma unroll
        for (int dsub = 0; dsub < 4; ++dsub)
            attnb[((size_t)t * Bb + b) * Ee + h*HD + dsub*16 + lr] =
                f2bf(oacc[dsub][reg] * inv);
    }
    if (lg == 0)
        lbuf[(size_t)bh * Tt + t0 + 16*w + lr] = lacc;
}

// ---------------------------------------------------------------------------
// MFMA avg_w pass (bf16 Q/K in): block = (b, 64 t, 64 s); loops 16 heads.
// Double-buffered h-loop (R23-validated).
// ---------------------------------------------------------------------------
__global__ __launch_bounds__(256)
void avg_probs_mfma(const unsigned short* __restrict__ qb, const unsigned short* __restrict__ kb,
                    const float* __restrict__ mask, const float* __restrict__ lbuf,
                    float* __restrict__ avg)
{
    __shared__ __align__(16) unsigned short Qs[2][64*66];
    __shared__ __align__(16) unsigned short Ksh[2][64*66];
    __shared__ float linv[16][64];

    const int tid  = threadIdx.x;
    const int b    = blockIdx.z;
    const int t0   = blockIdx.y * 64;
    const int s0   = blockIdx.x * 64;
    const int w    = tid >> 6;
    const int lane = tid & 63;
    const int lr   = lane & 15;
    const int lg   = lane >> 4;

    const int str = tid >> 2;              // staging row 0..63
    const int stc = (tid & 3) * 16;        // staging col (ushorts)

    {   // stage 1/(16*l) for all 16 heads + head 0's Q/K tiles
        const int hh = tid >> 4, tl = (tid & 15) * 4;
        const float4 lv = *(const float4*)&lbuf[(size_t)(b*Hh + hh) * Tt + t0 + tl];
        linv[hh][tl+0] = 1.f / (16.f * lv.x);
        linv[hh][tl+1] = 1.f / (16.f * lv.y);
        linv[hh][tl+2] = 1.f / (16.f * lv.z);
        linv[hh][tl+3] = 1.f / (16.f * lv.w);

        const unsigned short* Qp = &qb[((size_t)(b*Hh) * Tt + t0 + str) * HD + stc];
        const unsigned short* Kp = &kb[((size_t)(b*Hh) * Tt + s0 + str) * HD + stc];
        const uint4 q0 = *(const uint4*)Qp;
        const uint4 q1 = *(const uint4*)(Qp + 8);
        const uint4 k0 = *(const uint4*)Kp;
        const uint4 k1 = *(const uint4*)(Kp + 8);
        *(uint4*)&Qs[0][str*66 + stc]      = q0;
        *(uint4*)&Qs[0][str*66 + stc + 8]  = q1;
        *(uint4*)&Ksh[0][str*66 + stc]     = k0;
        *(uint4*)&Ksh[0][str*66 + stc + 8] = k1;
        __syncthreads();
    }

    // mask fragments (value(lane,reg) at t=t0+16w+4lg+reg, s=s0+16ssub+lr)
    f32x4 mf[4];
#pragma unroll
    for (int ssub = 0; ssub < 4; ++ssub)
#pragma unroll
        for (int reg = 0; reg < 4; ++reg)
            mf[ssub][reg] = mask[(size_t)(t0 + 16*w + 4*lg + reg) * Tt + s0 + 16*ssub + lr];

    f32x4 av[4];
#pragma unroll
    for (int ssub = 0; ssub < 4; ++ssub) av[ssub] = f32x4{0.f, 0.f, 0.f, 0.f};

    int cur = 0;
    for (int h = 0; h < Hh; ++h) {
        const bool has_next = (h + 1 < Hh);
        uint4 qn0, qn1, kn0, kn1;
        if (has_next) {
            const unsigned short* Qp = &qb[((size_t)(b*Hh + h + 1) * Tt + t0 + str) * HD + stc];
            const unsigned short* Kp = &kb[((size_t)(b*Hh + h + 1) * Tt + s0 + str) * HD + stc];
            qn0 = *(const uint4*)Qp;
            qn1 = *(const uint4*)(Qp + 8);
            kn0 = *(const uint4*)Kp;
            kn1 = *(const uint4*)(Kp + 8);
        }

        const unsigned short* Qc = &Qs[cur][0];
        const unsigned short* Kc = &Ksh[cur][0];

        const float lv0 = linv[h][16*w + 4*lg + 0];
        const float lv1 = linv[h][16*w + 4*lg + 1];
        const float lv2 = linv[h][16*w + 4*lg + 2];
        const float lv3 = linv[h][16*w + 4*lg + 3];

        const bf16x8 af0 = ldfrag(Qc, 16*w + lr, 4*lg);
        const bf16x8 af1 = ldfrag(Qc, 16*w + lr, 32 + 4*lg);
#pragma unroll
        for (int ssub = 0; ssub < 4; ++ssub) {
            const bf16x8 bf0 = ldfrag(Kc, 16*ssub + lr, 4*lg);
            const bf16x8 bf1 = ldfrag(Kc, 16*ssub + lr, 32 + 4*lg);
            f32x4 z = {0.f, 0.f, 0.f, 0.f};
            z = MFMA16(af0, bf0, z);
            z = MFMA16(af1, bf1, z);
            av[ssub][0] += __expf(z[0] + mf[ssub][0]) * lv0;
            av[ssub][1] += __expf(z[1] + mf[ssub][1]) * lv1;
            av[ssub][2] += __expf(z[2] + mf[ssub][2]) * lv2;
            av[ssub][3] += __expf(z[3] + mf[ssub][3]) * lv3;
        }

        if (has_next) {
            *(uint4*)&Qs[cur ^ 1][str*66 + stc]      = qn0;
            *(uint4*)&Qs[cur ^ 1][str*66 + stc + 8]  = qn1;
            *(uint4*)&Ksh[cur ^ 1][str*66 + stc]     = kn0;
            *(uint4*)&Ksh[cur ^ 1][str*66 + stc + 8] = kn1;
        }
        __syncthreads();
        cur ^= 1;
    }

#pragma unroll
    for (int ssub = 0; ssub < 4; ++ssub)
#pragma unroll
        for (int reg = 0; reg < 4; ++reg)
            avg[((size_t)b * Tt + t0 + 16*w + 4*lg + reg) * Tt + s0 + 16*ssub + lr] =
                av[ssub][reg];
}

// ---------------------------------------------------------------------------
extern "C" void kernel_launch(void* const* d_in, const int* in_sizes, int n_in,
                              void* d_out, int out_size, void* d_ws, size_t ws_size,
                              hipStream_t stream)
{
    (void)in_sizes; (void)n_in; (void)out_size; (void)ws_size;
    const float* query = (const float*)d_in[0];   // [T,B,E]
    const float* mask  = (const float*)d_in[1];   // [T,T]
    const float* Wqkv  = (const float*)d_in[2];   // [3E,E]
    const float* bqkv  = (const float*)d_in[3];   // [3E]
    const float* Wout  = (const float*)d_in[4];   // [E,E]
    const float* bout  = (const float*)d_in[5];   // [E]

    float* out = (float*)d_out;                   // [T,B,E]
    float* avg = out + (size_t)Tt * Bb * Ee;      // [B,T,T]

    const size_t S1 = (size_t)BHh * Tt * HD;      // 4,194,304
    unsigned short* wsu     = (unsigned short*)d_ws;
    unsigned short* qbuf    = wsu;                 // bf16, Q pre-scaled
    unsigned short* kbuf    = qbuf + S1;
    unsigned short* vbuf    = kbuf + S1;
    unsigned short* attnb   = vbuf + S1;           // bf16 [T*B][E]
    unsigned short* querybf = attnb + (size_t)Mm * Ee;
    unsigned short* wqkvbf  = querybf + (size_t)Mm * Ee;
    unsigned short* woutbf  = wqkvbf + (size_t)3 * Ee * Ee;
    float*          lbuf    = (float*)(woutbf + (size_t)Ee * Ee);

    // 0) prepack f32 weights/activations to bf16 (RNE)
    to_bf16<<<1024, 256, 0, stream>>>(query, querybf, (Mm*Ee)/8);
    to_bf16<<<1024, 256, 0, stream>>>(Wqkv, wqkvbf, (3*Ee*Ee)/8);
    to_bf16<<<512,  256, 0, stream>>>(Wout, woutbf, (Ee*Ee)/8);

    // 1) fused QKV projection (MFMA, dbuf; scatter bf16 head-major, scale Q)
    gemm_mfma<0><<<dim3(3072/128, Mm/128), 256, 0, stream>>>(
        querybf, wqkvbf, bqkv, nullptr, qbuf, kbuf, vbuf, 3072, Ee);
    // 2) MFMA fused attention — 128-row Q-tiles (R21/R23 config), dbuf
    attn_mfma<<<dim3(BHh * (Tt/128)), 512, 0, stream>>>(
        qbuf, kbuf, vbuf, mask, attnb, lbuf);
    // 3) head-averaged probs (MFMA, dbuf h-loop)
    avg_probs_mfma<<<dim3(Tt/64, Tt/64, Bb), 256, 0, stream>>>(
        qbuf, kbuf, mask, lbuf, avg);
    // 4) output projection (MFMA, dbuf)
    gemm_mfma<1><<<dim3(Ee/128, Mm/128), 256, 0, stream>>>(
        attnb, woutbf, bout, out, nullptr, nullptr, nullptr, Ee, Ee);
}